// Round 1
// baseline (327.883 us; speedup 1.0000x reference)
//
#include <hip/hip_runtime.h>

typedef unsigned short u16;
typedef unsigned int u32;
typedef float f32x4 __attribute__((ext_vector_type(4)));
typedef int i32x4 __attribute__((ext_vector_type(4)));
typedef __bf16 bf16x8 __attribute__((ext_vector_type(8)));
typedef short s16x8 __attribute__((ext_vector_type(8)));

#define CN0 655360
#define CN1 81920
#define CN2 8192

// ---------------- ws layout (bytes) ----------------
#define H0_OFF    0ull            // u16[81920*256] (l2normed layer0 out; later reused as m1)
#define T_OFF     41943040ull     // u16[81920*256] (hidden pre-bn t)
#define H2_OFF    83886080ull     // u16[8192*256]  (relu(bnh(t)) head rows)
#define ZZ_OFF    88080384ull     // f32[8192*256]  (pre-bnl latent)
#define WP0F_OFF  96468992ull     // u16[128*128] frag
#define WC0F_OFF  96501760ull     // u16[256*256] frag [Wself0;Wneigh0]
#define WHF_OFF   96632832ull     // u16[256*256] frag
#define WP1F_OFF  96763904ull     // u16[256*256] frag
#define WC1F_OFF  96894976ull     // u16[512*256] frag [Wself1;Wneigh1]
#define WLATF_OFF 97157120ull     // u16[256*256] frag
#define STAT_OFF  97288192ull     // f32[6*256]: bn0 sum/sumsq, bnh, bnl
#define SS_OFF    97294336ull     // f32[6*256]: scale/shift bn0, bnh, bnl

__device__ inline u16 f2bf(float f) {
  u32 u = __builtin_bit_cast(u32, f);
  return (u16)((u + 0x7fffu + ((u >> 16) & 1u)) >> 16);  // RNE
}
__device__ inline float bf2f(u16 s) {
  return __builtin_bit_cast(float, (u32)s << 16);
}

// MFMA shim: gfx950 builtin takes either v8bf16 or v8i16 depending on
// toolchain; SFINAE picks whichever compiles.
template <typename V>
__device__ inline auto mfma_sel(V a, V b, f32x4 c, int)
    -> decltype(__builtin_amdgcn_mfma_f32_16x16x32_bf16(a, b, c, 0, 0, 0)) {
  return __builtin_amdgcn_mfma_f32_16x16x32_bf16(a, b, c, 0, 0, 0);
}
template <typename V>
__device__ inline f32x4 mfma_sel(V a, V b, f32x4 c, long) {
  return __builtin_amdgcn_mfma_f32_16x16x32_bf16(
      __builtin_bit_cast(s16x8, a), __builtin_bit_cast(s16x8, b), c, 0, 0, 0);
}
__device__ inline f32x4 MFMA(i32x4 a, i32x4 b, f32x4 c) {
  return mfma_sel(__builtin_bit_cast(bf16x8, a), __builtin_bit_cast(bf16x8, b), c, 0);
}

// ---------------- weight prep: bf16 + MFMA-B fragment order ----------------
// storage [kt][nt][lane][j]; value = B[kt*32 + 8*(lane>>4) + j][nt*16 + (lane&15)]
__device__ void fragify(const float* W0, const float* W1, int Khalf, int N,
                        u16* dst, int tid, int nthr) {
  int K = W1 ? 2 * Khalf : Khalf;
  int ntile = N >> 4;
  int total = (K >> 5) * ntile * 512;
  for (int i = tid; i < total; i += nthr) {
    int j = i & 7;
    int lane = (i >> 3) & 63;
    int nt = (i >> 9) % ntile;
    int kt = i / (512 * ntile);
    int k = kt * 32 + ((lane >> 4) << 3) + j;
    int n = nt * 16 + (lane & 15);
    float v = (k < Khalf) ? W0[k * N + n] : W1[(k - Khalf) * N + n];
    dst[i] = f2bf(v);
  }
}

__global__ void kprep(const float* Wp0, const float* Ws0, const float* Wn0,
                      const float* Wh, const float* Wp1, const float* Ws1,
                      const float* Wn1, const float* Wlat,
                      u16* wp0f, u16* wc0f, u16* whf, u16* wp1f, u16* wc1f,
                      u16* wlatf) {
  int tid = blockIdx.x * blockDim.x + threadIdx.x;
  int nthr = gridDim.x * blockDim.x;
  fragify(Wp0, nullptr, 128, 128, wp0f, tid, nthr);
  fragify(Ws0, Wn0, 128, 256, wc0f, tid, nthr);
  fragify(Wh, nullptr, 256, 256, whf, tid, nthr);
  fragify(Wp1, nullptr, 256, 256, wp1f, tid, nthr);
  fragify(Ws1, Wn1, 256, 256, wc1f, tid, nthr);
  fragify(Wlat, nullptr, 256, 256, wlatf, tid, nthr);
}

// ---------------- BN finalize: stats -> per-col scale/shift ----------------
__global__ void kfin(const float* __restrict__ stat, float inv_n,
                     const float* __restrict__ g, const float* __restrict__ be,
                     float* __restrict__ ssout) {
  int c = threadIdx.x;
  float mu = stat[c] * inv_n;
  float var = stat[256 + c] * inv_n - mu * mu;
  float sc = g[c] / sqrtf(var + 1e-5f);
  ssout[c] = sc;
  ssout[256 + c] = be[c] - mu * sc;
}

// ---------------- K1: fused layer-0 SAGE (32 dst / block) ----------------
__global__ __launch_bounds__(256, 2)
void k1_layer0(const float* __restrict__ x, const int* __restrict__ esrc,
               const u16* __restrict__ wp0f, const u16* __restrict__ wc0f,
               const float* __restrict__ bp0, const float* __restrict__ b0v,
               u16* __restrict__ h0, float* __restrict__ stat0) {
  __shared__ __align__(16) char lds[81920];
  float* pooled = (float*)(lds + 65536);   // [32][128] f32
  int tid = threadIdx.x, lane = tid & 63, w = tid >> 6;
  int r15 = lane & 15, g = lane >> 4;
  int d0 = blockIdx.x * 32;

  // ---- gather 256 edge-src rows of x -> swizzled bf16 LDS [256][128]
  {
    int r = tid;
    int src = esrc[d0 * 8 + r];
    const float* xr = x + (size_t)src * 128;
    u32 rowb = (u32)r * 256, sw = (u32)((r & 7) << 4);
    for (int c = 0; c < 16; ++c) {
      f32x4 p0 = *(const f32x4*)(xr + c * 8);
      f32x4 p1 = *(const f32x4*)(xr + c * 8 + 4);
      union { i32x4 q; u16 h[8]; } pk;
      #pragma unroll
      for (int j = 0; j < 4; ++j) { pk.h[j] = f2bf(p0[j]); pk.h[4 + j] = f2bf(p1[j]); }
      *(i32x4*)(lds + ((rowb + (u32)c * 16) ^ sw)) = pk.q;
    }
  }
  __syncthreads();

  // ---- phase A: m = relu(xg @ Wp0 + bp0), segmented max(8) -> pooled
  {
    i32x4 afr[4][4];
    #pragma unroll
    for (int rt = 0; rt < 4; ++rt)
      #pragma unroll
      for (int kt = 0; kt < 4; ++kt) {
        u32 r = (u32)(w * 64 + rt * 16 + r15);
        afr[rt][kt] = *(const i32x4*)(lds + ((r * 256 + (u32)kt * 64 + (u32)g * 16) ^ ((r & 7) << 4)));
      }
    for (int nt = 0; nt < 8; ++nt) {
      f32x4 acc[4] = {};
      #pragma unroll
      for (int kt = 0; kt < 4; ++kt) {
        i32x4 b = *(const i32x4*)(wp0f + (((kt * 8 + nt) * 64 + lane) << 3));
        #pragma unroll
        for (int rt = 0; rt < 4; ++rt) acc[rt] = MFMA(afr[rt][kt], b, acc[rt]);
      }
      float bias = bp0[nt * 16 + r15];
      #pragma unroll
      for (int rt = 0; rt < 4; ++rt) {
        float mx = fmaxf(fmaxf(acc[rt][0], acc[rt][1]), fmaxf(acc[rt][2], acc[rt][3]));
        mx = fmaxf(mx + bias, 0.0f);                 // relu(max+bias) == max(relu(v+bias))
        mx = fmaxf(mx, __shfl_xor(mx, 16));          // combine row-groups 0-3/4-7 (or 8-11/12-15)
        if ((g & 1) == 0)
          pooled[(w * 8 + rt * 2 + (g >> 1)) * 128 + nt * 16 + r15] = mx;
      }
    }
  }
  __syncthreads();

  // ---- phase B: u = [x_dst | pooled] (bf16, swizzled [32][256]) at lds[0:16K]
  float* h0buf = (float*)(lds + 16384);   // [32][256] f32
  {
    int i = tid >> 3, seg = tid & 7;
    int k0 = seg * 32;
    u32 sw = (u32)((i & 7) << 4);
    float vals[32];
    if (seg < 4) {
      const float* xr = x + (size_t)(d0 + i) * 128 + k0;
      #pragma unroll
      for (int c4 = 0; c4 < 8; ++c4) {
        f32x4 t = *(const f32x4*)(xr + c4 * 4);
        vals[c4 * 4 + 0] = t[0]; vals[c4 * 4 + 1] = t[1];
        vals[c4 * 4 + 2] = t[2]; vals[c4 * 4 + 3] = t[3];
      }
    } else {
      const float* pr = pooled + i * 128 + (k0 - 128);
      #pragma unroll
      for (int c4 = 0; c4 < 8; ++c4) {
        f32x4 t = *(const f32x4*)(pr + c4 * 4);
        vals[c4 * 4 + 0] = t[0]; vals[c4 * 4 + 1] = t[1];
        vals[c4 * 4 + 2] = t[2]; vals[c4 * 4 + 3] = t[3];
      }
    }
    #pragma unroll
    for (int cc = 0; cc < 4; ++cc) {
      union { i32x4 q; u16 h[8]; } pk;
      #pragma unroll
      for (int j = 0; j < 8; ++j) pk.h[j] = f2bf(vals[cc * 8 + j]);
      *(i32x4*)(lds + (((u32)i * 512 + (u32)(k0 + cc * 8) * 2) ^ sw)) = pk.q;
    }
  }
  __syncthreads();

  // ---- phase B GEMM: h0row = u @ Wcat0 + b0
  {
    f32x4 acc[4][2] = {};
    for (int kt = 0; kt < 8; ++kt) {
      u32 r0 = (u32)r15, r1 = (u32)(16 + r15);
      i32x4 a0 = *(const i32x4*)(lds + ((r0 * 512 + (u32)kt * 64 + (u32)g * 16) ^ ((r0 & 7) << 4)));
      i32x4 a1 = *(const i32x4*)(lds + ((r1 * 512 + (u32)kt * 64 + (u32)g * 16) ^ ((r1 & 7) << 4)));
      #pragma unroll
      for (int n4 = 0; n4 < 4; ++n4) {
        int nt = w * 4 + n4;
        i32x4 b = *(const i32x4*)(wc0f + (((size_t)(kt * 16 + nt) * 64 + lane) << 3));
        acc[n4][0] = MFMA(a0, b, acc[n4][0]);
        acc[n4][1] = MFMA(a1, b, acc[n4][1]);
      }
    }
    #pragma unroll
    for (int n4 = 0; n4 < 4; ++n4) {
      int col = (w * 4 + n4) * 16 + r15;
      float bv = b0v[col];
      #pragma unroll
      for (int rt = 0; rt < 2; ++rt)
        #pragma unroll
        for (int j = 0; j < 4; ++j)
          h0buf[(rt * 16 + g * 4 + j) * 256 + col] = acc[n4][rt][j] + bv;
    }
  }
  __syncthreads();

  // ---- l2norm rows + global bf16 write
  {
    int i = tid >> 3, part = tid & 7;
    float* hr = h0buf + i * 256 + part * 32;
    float v[32]; float ss = 0.0f;
    #pragma unroll
    for (int c = 0; c < 32; ++c) { v[c] = hr[c]; ss += v[c] * v[c]; }
    ss += __shfl_xor(ss, 1); ss += __shfl_xor(ss, 2); ss += __shfl_xor(ss, 4);
    float rn = 1.0f / fmaxf(sqrtf(ss), 1e-12f);
    u16* orow = h0 + (size_t)(d0 + i) * 256 + part * 32;
    #pragma unroll
    for (int cc = 0; cc < 4; ++cc) {
      union { i32x4 q; u16 h[8]; } pk;
      #pragma unroll
      for (int j = 0; j < 8; ++j) {
        float nv = v[cc * 8 + j] * rn;
        hr[cc * 8 + j] = nv;
        pk.h[j] = f2bf(nv);
      }
      *(i32x4*)(orow + cc * 8) = pk.q;
    }
  }
  __syncthreads();

  // ---- bn0 column partial stats
  {
    int c = tid; float s1 = 0.0f, s2 = 0.0f;
    for (int r = 0; r < 32; ++r) { float vv = h0buf[r * 256 + c]; s1 += vv; s2 += vv * vv; }
    atomicAdd(&stat0[c], s1); atomicAdd(&stat0[256 + c], s2);
  }
}

// ---------------- gemm64: Out = [relu(affine(Ain))] @ Bf + bias ----------------
template <bool RELU_OUT, bool STATS, bool H2OUT>
__global__ __launch_bounds__(256, 2)
void gemm64(const u16* __restrict__ Ain, const float* __restrict__ ss,
            const u16* __restrict__ Bf, const float* __restrict__ bias,
            u16* __restrict__ Out, float* __restrict__ stat,
            u16* __restrict__ H2out) {
  __shared__ __align__(16) char lds[67584];
  u16* tb = (u16*)(lds + 32768);          // [64][256] plain bf16
  float* scs = (float*)(lds + 65536);     // 512 f32
  int tid = threadIdx.x, lane = tid & 63, w = tid >> 6;
  int r15 = lane & 15, g = lane >> 4;
  int d0 = blockIdx.x * 64;
  scs[tid] = ss[tid];
  scs[256 + tid] = ss[256 + tid];
  __syncthreads();

  // A-build: relu(scale*a + shift) -> swizzled bf16 [64][256]
  {
    int i = tid >> 2, part = tid & 3;
    const u16* ar = Ain + (size_t)(d0 + i) * 256 + part * 64;
    u32 sw = (u32)((i & 7) << 4), rowb = (u32)i * 512;
    for (int cc = 0; cc < 8; ++cc) {
      union { i32x4 q; u16 h[8]; } in, out;
      in.q = *(const i32x4*)(ar + cc * 8);
      #pragma unroll
      for (int j = 0; j < 8; ++j) {
        int k = part * 64 + cc * 8 + j;
        float v = fmaxf(bf2f(in.h[j]) * scs[k] + scs[256 + k], 0.0f);
        out.h[j] = f2bf(v);
      }
      *(i32x4*)(lds + ((rowb + (u32)(part * 64 + cc * 8) * 2) ^ sw)) = out.q;
    }
  }
  __syncthreads();

  f32x4 acc[4][4] = {};   // [n4][rt]
  for (int kt = 0; kt < 8; ++kt) {
    i32x4 a[4];
    #pragma unroll
    for (int rt = 0; rt < 4; ++rt) {
      u32 r = (u32)(rt * 16 + r15);
      a[rt] = *(const i32x4*)(lds + ((r * 512 + (u32)kt * 64 + (u32)g * 16) ^ ((r & 7) << 4)));
    }
    #pragma unroll
    for (int n4 = 0; n4 < 4; ++n4) {
      int nt = w * 4 + n4;
      i32x4 b = *(const i32x4*)(Bf + (((size_t)(kt * 16 + nt) * 64 + lane) << 3));
      #pragma unroll
      for (int rt = 0; rt < 4; ++rt) acc[n4][rt] = MFMA(a[rt], b, acc[n4][rt]);
    }
  }
  #pragma unroll
  for (int n4 = 0; n4 < 4; ++n4) {
    int col = (w * 4 + n4) * 16 + r15;
    float bv = bias[col];
    #pragma unroll
    for (int rt = 0; rt < 4; ++rt)
      #pragma unroll
      for (int j = 0; j < 4; ++j) {
        float v = acc[n4][rt][j] + bv;
        if (RELU_OUT) v = fmaxf(v, 0.0f);
        tb[(rt * 16 + g * 4 + j) * 256 + col] = f2bf(v);
      }
  }
  __syncthreads();

  {
    int i = tid >> 2, part = tid & 3;
    u16* orow = Out + (size_t)(d0 + i) * 256 + part * 64;
    const u16* trow = tb + i * 256 + part * 64;
    #pragma unroll
    for (int cc = 0; cc < 8; ++cc)
      *(i32x4*)(orow + cc * 8) = *(const i32x4*)(trow + cc * 8);
  }
  if (STATS) {
    int c = tid; float s1 = 0.0f, s2 = 0.0f;
    for (int r = 0; r < 64; ++r) { float v = bf2f(tb[r * 256 + c]); s1 += v; s2 += v * v; }
    atomicAdd(&stat[c], s1); atomicAdd(&stat[256 + c], s2);
  }
  if (H2OUT && d0 < CN2) {
    int i = tid >> 2, part = tid & 3;
    u16* orow = H2out + (size_t)(d0 + i) * 256 + part * 64;
    u32 sw = (u32)((i & 7) << 4);
    #pragma unroll
    for (int cc = 0; cc < 8; ++cc)
      *(i32x4*)(orow + cc * 8) =
          *(const i32x4*)(lds + (((u32)i * 512 + (u32)(part * 64 + cc * 8) * 2) ^ sw));
  }
}

// ---------------- K6: fused layer-1 (32 dst / block) ----------------
__global__ __launch_bounds__(256, 2)
void k6_layer1(const int* __restrict__ esrc1, const u16* __restrict__ m1,
               const u16* __restrict__ h2, const u16* __restrict__ wc1f,
               const u16* __restrict__ wlatf, const float* __restrict__ b1v,
               const float* __restrict__ blat, float* __restrict__ zz,
               float* __restrict__ statl) {
  __shared__ __align__(16) char lds[81920];
  // u1 swizzled bf16 [32][512] @0; zbuf f32 [32][256] @32768; u2 swizzled bf16 [32][256] @65536
  float* zbuf = (float*)(lds + 32768);
  int tid = threadIdx.x, lane = tid & 63, w = tid >> 6;
  int r15 = lane & 15, g = lane >> 4;
  int d0 = blockIdx.x * 32;

  // ---- build u1 = [h2_dst | max-pool(m1 rows)]
  {
    int i = tid >> 3, part = tid & 7;
    u32 sw = (u32)((i & 7) << 4);
    const u16* hrow = h2 + (size_t)(d0 + i) * 256 + part * 32;
    #pragma unroll
    for (int cc = 0; cc < 4; ++cc) {
      i32x4 q = *(const i32x4*)(hrow + cc * 8);
      *(i32x4*)(lds + (((u32)i * 1024 + (u32)(part * 32 + cc * 8) * 2) ^ sw)) = q;
    }
    float mx[32];
    #pragma unroll
    for (int c = 0; c < 32; ++c) mx[c] = -1e30f;
    for (int e = 0; e < 10; ++e) {
      int src = esrc1[(d0 + i) * 10 + e];
      const u16* mrow = m1 + (size_t)src * 256 + part * 32;
      #pragma unroll
      for (int cc = 0; cc < 4; ++cc) {
        union { i32x4 q; u16 h[8]; } pk;
        pk.q = *(const i32x4*)(mrow + cc * 8);
        #pragma unroll
        for (int j = 0; j < 8; ++j) mx[cc * 8 + j] = fmaxf(mx[cc * 8 + j], bf2f(pk.h[j]));
      }
    }
    #pragma unroll
    for (int cc = 0; cc < 4; ++cc) {
      union { i32x4 q; u16 h[8]; } pk;
      #pragma unroll
      for (int j = 0; j < 8; ++j) pk.h[j] = f2bf(mx[cc * 8 + j]);
      *(i32x4*)(lds + (((u32)i * 1024 + (u32)(256 + part * 32 + cc * 8) * 2) ^ sw)) = pk.q;
    }
  }
  __syncthreads();

  // ---- GEMM1: z = u1 @ Wcat1 + b1 -> zbuf
  {
    f32x4 acc[4][2] = {};
    for (int kt = 0; kt < 16; ++kt) {
      u32 r0 = (u32)r15, r1 = (u32)(16 + r15);
      i32x4 a0 = *(const i32x4*)(lds + ((r0 * 1024 + (u32)kt * 64 + (u32)g * 16) ^ ((r0 & 7) << 4)));
      i32x4 a1 = *(const i32x4*)(lds + ((r1 * 1024 + (u32)kt * 64 + (u32)g * 16) ^ ((r1 & 7) << 4)));
      #pragma unroll
      for (int n4 = 0; n4 < 4; ++n4) {
        int nt = w * 4 + n4;
        i32x4 b = *(const i32x4*)(wc1f + (((size_t)(kt * 16 + nt) * 64 + lane) << 3));
        acc[n4][0] = MFMA(a0, b, acc[n4][0]);
        acc[n4][1] = MFMA(a1, b, acc[n4][1]);
      }
    }
    #pragma unroll
    for (int n4 = 0; n4 < 4; ++n4) {
      int col = (w * 4 + n4) * 16 + r15;
      float bv = b1v[col];
      #pragma unroll
      for (int rt = 0; rt < 2; ++rt)
        #pragma unroll
        for (int j = 0; j < 4; ++j)
          zbuf[(rt * 16 + g * 4 + j) * 256 + col] = acc[n4][rt][j] + bv;
    }
  }
  __syncthreads();

  // ---- l2norm -> u2 (swizzled bf16 @65536)
  {
    int i = tid >> 3, part = tid & 7;
    float* zr = zbuf + i * 256 + part * 32;
    float v[32]; float ss = 0.0f;
    #pragma unroll
    for (int c = 0; c < 32; ++c) { v[c] = zr[c]; ss += v[c] * v[c]; }
    ss += __shfl_xor(ss, 1); ss += __shfl_xor(ss, 2); ss += __shfl_xor(ss, 4);
    float rn = 1.0f / fmaxf(sqrtf(ss), 1e-12f);
    u32 sw = (u32)((i & 7) << 4);
    #pragma unroll
    for (int cc = 0; cc < 4; ++cc) {
      union { i32x4 q; u16 h[8]; } pk;
      #pragma unroll
      for (int j = 0; j < 8; ++j) pk.h[j] = f2bf(v[cc * 8 + j] * rn);
      *(i32x4*)(lds + 65536 + (((u32)i * 512 + (u32)(part * 32 + cc * 8) * 2) ^ sw)) = pk.q;
    }
  }
  __syncthreads();

  // ---- GEMM2: zz_blk = u2 @ Wlat + blat -> zbuf (overwrite)
  {
    f32x4 acc[4][2] = {};
    for (int kt = 0; kt < 8; ++kt) {
      u32 r0 = (u32)r15, r1 = (u32)(16 + r15);
      i32x4 a0 = *(const i32x4*)(lds + 65536 + ((r0 * 512 + (u32)kt * 64 + (u32)g * 16) ^ ((r0 & 7) << 4)));
      i32x4 a1 = *(const i32x4*)(lds + 65536 + ((r1 * 512 + (u32)kt * 64 + (u32)g * 16) ^ ((r1 & 7) << 4)));
      #pragma unroll
      for (int n4 = 0; n4 < 4; ++n4) {
        int nt = w * 4 + n4;
        i32x4 b = *(const i32x4*)(wlatf + (((size_t)(kt * 16 + nt) * 64 + lane) << 3));
        acc[n4][0] = MFMA(a0, b, acc[n4][0]);
        acc[n4][1] = MFMA(a1, b, acc[n4][1]);
      }
    }
    #pragma unroll
    for (int n4 = 0; n4 < 4; ++n4) {
      int col = (w * 4 + n4) * 16 + r15;
      float bv = blat[col];
      #pragma unroll
      for (int rt = 0; rt < 2; ++rt)
        #pragma unroll
        for (int j = 0; j < 4; ++j)
          zbuf[(rt * 16 + g * 4 + j) * 256 + col] = acc[n4][rt][j] + bv;
    }
  }
  __syncthreads();

  // ---- write zz + bnl stats
  {
    int i = tid >> 3, part = tid & 7;
    float* zr = zbuf + i * 256 + part * 32;
    float* orow = zz + (size_t)(d0 + i) * 256 + part * 32;
    #pragma unroll
    for (int c = 0; c < 32; c += 4) *(f32x4*)(orow + c) = *(const f32x4*)(zr + c);
  }
  {
    int c = tid; float s1 = 0.0f, s2 = 0.0f;
    for (int r = 0; r < 32; ++r) { float v = zbuf[r * 256 + c]; s1 += v; s2 += v * v; }
    atomicAdd(&statl[c], s1); atomicAdd(&statl[256 + c], s2);
  }
}

// ---------------- K7: out = bnl(zz) ----------------
__global__ void k7_out(const float* __restrict__ zz, const float* __restrict__ ssl,
                       float* __restrict__ out) {
  int idx = blockIdx.x * 256 + threadIdx.x;
  int e0 = idx * 4;
  int c = e0 & 255;
  f32x4 v = *(const f32x4*)(zz + e0);
  f32x4 sc = *(const f32x4*)(ssl + c);
  f32x4 sh = *(const f32x4*)(ssl + 256 + c);
  *(f32x4*)(out + e0) = v * sc + sh;
}

extern "C" void kernel_launch(void* const* d_in, const int* in_sizes, int n_in,
                              void* d_out, int out_size, void* d_ws, size_t ws_size,
                              hipStream_t stream) {
  const float* x     = (const float*)d_in[0];
  const int*   es0   = (const int*)d_in[1];
  const int*   es1   = (const int*)d_in[3];
  const float* Wp0   = (const float*)d_in[5];
  const float* bp0   = (const float*)d_in[6];
  const float* Ws0   = (const float*)d_in[7];
  const float* Wn0   = (const float*)d_in[8];
  const float* b0v   = (const float*)d_in[9];
  const float* Wp1   = (const float*)d_in[10];
  const float* bp1   = (const float*)d_in[11];
  const float* Ws1   = (const float*)d_in[12];
  const float* Wn1   = (const float*)d_in[13];
  const float* b1v   = (const float*)d_in[14];
  const float* gbn0  = (const float*)d_in[15];
  const float* bebn0 = (const float*)d_in[16];
  const float* Wh    = (const float*)d_in[17];
  const float* bh    = (const float*)d_in[18];
  const float* gbnh  = (const float*)d_in[19];
  const float* bebnh = (const float*)d_in[20];
  const float* Wlat  = (const float*)d_in[21];
  const float* blat  = (const float*)d_in[22];
  const float* gbnl  = (const float*)d_in[23];
  const float* bebnl = (const float*)d_in[24];

  char* ws = (char*)d_ws;
  u16* h0    = (u16*)(ws + H0_OFF);
  u16* tban  = (u16*)(ws + T_OFF);
  u16* m1    = (u16*)(ws + H0_OFF);   // reuse: h0 dead after hidden GEMM
  u16* h2    = (u16*)(ws + H2_OFF);
  float* zz  = (float*)(ws + ZZ_OFF);
  u16* wp0f  = (u16*)(ws + WP0F_OFF);
  u16* wc0f  = (u16*)(ws + WC0F_OFF);
  u16* whf   = (u16*)(ws + WHF_OFF);
  u16* wp1f  = (u16*)(ws + WP1F_OFF);
  u16* wc1f  = (u16*)(ws + WC1F_OFF);
  u16* wlatf = (u16*)(ws + WLATF_OFF);
  float* stat = (float*)(ws + STAT_OFF);
  float* ssv  = (float*)(ws + SS_OFF);

  hipMemsetAsync(stat, 0, 6 * 256 * sizeof(float), stream);
  kprep<<<64, 256, 0, stream>>>(Wp0, Ws0, Wn0, Wh, Wp1, Ws1, Wn1, Wlat,
                                wp0f, wc0f, whf, wp1f, wc1f, wlatf);
  k1_layer0<<<CN1 / 32, 256, 0, stream>>>(x, es0, wp0f, wc0f, bp0, b0v, h0, stat);
  kfin<<<1, 256, 0, stream>>>(stat, 1.0f / CN1, gbn0, bebn0, ssv);
  gemm64<false, true, false><<<CN1 / 64, 256, 0, stream>>>(h0, ssv, whf, bh, tban,
                                                           stat + 512, nullptr);
  kfin<<<1, 256, 0, stream>>>(stat + 512, 1.0f / CN1, gbnh, bebnh, ssv + 512);
  gemm64<true, false, true><<<CN1 / 64, 256, 0, stream>>>(tban, ssv + 512, wp1f, bp1,
                                                          m1, nullptr, h2);
  k6_layer1<<<CN2 / 32, 256, 0, stream>>>(es1, m1, h2, wc1f, wlatf, b1v, blat, zz,
                                          stat + 1024);
  kfin<<<1, 256, 0, stream>>>(stat + 1024, 1.0f / CN2, gbnl, bebnl, ssv + 1024);
  k7_out<<<out_size / 1024, 256, 0, stream>>>(zz, ssv + 1024, (float*)d_out);
  (void)in_sizes; (void)n_in; (void)ws_size;
}

// Round 2
// 283.369 us; speedup vs baseline: 1.1571x; 1.1571x over previous
//
#include <hip/hip_runtime.h>

typedef unsigned short u16;
typedef unsigned int u32;
typedef float f32x4 __attribute__((ext_vector_type(4)));
typedef int i32x4 __attribute__((ext_vector_type(4)));
typedef __bf16 bf16x8 __attribute__((ext_vector_type(8)));
typedef short s16x8 __attribute__((ext_vector_type(8)));

#define CN0 655360
#define CN1 81920
#define CN2 8192

// ---------------- ws layout (bytes) ----------------
#define H0_OFF    0ull            // u16[81920*256] (l2normed layer0 out; later reused as m1)
#define T_OFF     41943040ull     // u16[81920*256] (hidden pre-bn t)
#define H2_OFF    83886080ull     // u16[8192*256]  (relu(bnh(t)) head rows)
#define ZZ_OFF    88080384ull     // f32[8192*256]  (pre-bnl latent)
#define WP0F_OFF  96468992ull     // u16[128*128] frag
#define WC0F_OFF  96501760ull     // u16[256*256] frag [Wself0;Wneigh0]
#define WHF_OFF   96632832ull     // u16[256*256] frag
#define WP1F_OFF  96763904ull     // u16[256*256] frag
#define WC1F_OFF  96894976ull     // u16[512*256] frag [Wself1;Wneigh1]
#define WLATF_OFF 97157120ull     // u16[256*256] frag
#define STAT_OFF  97288192ull     // f32[6*256]: bn0 sum/sumsq, bnh, bnl
#define SS_OFF    97294336ull     // f32[6*256]: scale/shift bn0, bnh, bnl

__device__ inline u16 f2bf(float f) {
  u32 u = __builtin_bit_cast(u32, f);
  return (u16)((u + 0x7fffu + ((u >> 16) & 1u)) >> 16);  // RNE
}
__device__ inline float bf2f(u16 s) {
  return __builtin_bit_cast(float, (u32)s << 16);
}
// 8×f32 -> packed bf16x8 (compiler emits v_cvt_pk_bf16_f32)
__device__ inline i32x4 cvt8(f32x4 a, f32x4 b) {
  union { bf16x8 v; i32x4 q; } u;
  #pragma unroll
  for (int j = 0; j < 4; ++j) { u.v[j] = (__bf16)a[j]; u.v[4 + j] = (__bf16)b[j]; }
  return u.q;
}

// MFMA shim: gfx950 builtin takes either v8bf16 or v8i16 depending on
// toolchain; SFINAE picks whichever compiles.
template <typename V>
__device__ inline auto mfma_sel(V a, V b, f32x4 c, int)
    -> decltype(__builtin_amdgcn_mfma_f32_16x16x32_bf16(a, b, c, 0, 0, 0)) {
  return __builtin_amdgcn_mfma_f32_16x16x32_bf16(a, b, c, 0, 0, 0);
}
template <typename V>
__device__ inline f32x4 mfma_sel(V a, V b, f32x4 c, long) {
  return __builtin_amdgcn_mfma_f32_16x16x32_bf16(
      __builtin_bit_cast(s16x8, a), __builtin_bit_cast(s16x8, b), c, 0, 0, 0);
}
__device__ inline f32x4 MFMA(i32x4 a, i32x4 b, f32x4 c) {
  return mfma_sel(__builtin_bit_cast(bf16x8, a), __builtin_bit_cast(bf16x8, b), c, 0);
}

// ---------------- weight prep: bf16 + MFMA-B fragment order ----------------
// storage [kt][nt][lane][j]; value = B[kt*32 + 8*(lane>>4) + j][nt*16 + (lane&15)]
__device__ void fragify(const float* W0, const float* W1, int Khalf, int N,
                        u16* dst, int tid, int nthr) {
  int K = W1 ? 2 * Khalf : Khalf;
  int ntile = N >> 4;
  int total = (K >> 5) * ntile * 512;
  for (int i = tid; i < total; i += nthr) {
    int j = i & 7;
    int lane = (i >> 3) & 63;
    int nt = (i >> 9) % ntile;
    int kt = i / (512 * ntile);
    int k = kt * 32 + ((lane >> 4) << 3) + j;
    int n = nt * 16 + (lane & 15);
    float v = (k < Khalf) ? W0[k * N + n] : W1[(k - Khalf) * N + n];
    dst[i] = f2bf(v);
  }
}

__global__ void kprep(const float* Wp0, const float* Ws0, const float* Wn0,
                      const float* Wh, const float* Wp1, const float* Ws1,
                      const float* Wn1, const float* Wlat,
                      u16* wp0f, u16* wc0f, u16* whf, u16* wp1f, u16* wc1f,
                      u16* wlatf) {
  int tid = blockIdx.x * blockDim.x + threadIdx.x;
  int nthr = gridDim.x * blockDim.x;
  fragify(Wp0, nullptr, 128, 128, wp0f, tid, nthr);
  fragify(Ws0, Wn0, 128, 256, wc0f, tid, nthr);
  fragify(Wh, nullptr, 256, 256, whf, tid, nthr);
  fragify(Wp1, nullptr, 256, 256, wp1f, tid, nthr);
  fragify(Ws1, Wn1, 256, 256, wc1f, tid, nthr);
  fragify(Wlat, nullptr, 256, 256, wlatf, tid, nthr);
}

// ---------------- BN finalize: stats -> per-col scale/shift ----------------
__global__ void kfin(const float* __restrict__ stat, float inv_n,
                     const float* __restrict__ g, const float* __restrict__ be,
                     float* __restrict__ ssout) {
  int c = threadIdx.x;
  float mu = stat[c] * inv_n;
  float var = stat[256 + c] * inv_n - mu * mu;
  float sc = g[c] / sqrtf(var + 1e-5f);
  ssout[c] = sc;
  ssout[256 + c] = be[c] - mu * sc;
}

// ---------------- K1: fused layer-0 SAGE (32 dst / block) ----------------
// A-fragments gathered DIRECTLY from global x (no staging LDS); LDS only
// holds the 16KB concat-u buffer + 512B rowsum buffer. 3 blocks/CU.
__global__ __launch_bounds__(256, 3)
void k1_layer0(const float* __restrict__ x, const int* __restrict__ esrc,
               const u16* __restrict__ wp0f, const u16* __restrict__ wc0f,
               const float* __restrict__ bp0, const float* __restrict__ b0v,
               u16* __restrict__ h0, float* __restrict__ stat0) {
  __shared__ __align__(16) char lds[16896];  // u [32][256]bf16 @0; rowsum f32[32][4] @16384
  float* rsb = (float*)(lds + 16384);
  int tid = threadIdx.x, lane = tid & 63, w = tid >> 6;
  int r15 = lane & 15, g = lane >> 4;
  int d0 = blockIdx.x * 32;

  // ---- phase A: gather A-fragments from global, m = relu(row@Wp0+bp0), segmax(8)
  {
    int e0 = d0 * 8 + w * 64;
    const float* rp[4];
    #pragma unroll
    for (int rt = 0; rt < 4; ++rt)
      rp[rt] = x + (size_t)esrc[e0 + rt * 16 + r15] * 128;
    i32x4 afr[4][4];
    #pragma unroll
    for (int rt = 0; rt < 4; ++rt)
      #pragma unroll
      for (int kt = 0; kt < 4; ++kt) {
        f32x4 p0 = *(const f32x4*)(rp[rt] + kt * 32 + g * 8);
        f32x4 p1 = *(const f32x4*)(rp[rt] + kt * 32 + g * 8 + 4);
        afr[rt][kt] = cvt8(p0, p1);
      }
    for (int nt = 0; nt < 8; ++nt) {
      f32x4 acc[4] = {};
      #pragma unroll
      for (int kt = 0; kt < 4; ++kt) {
        i32x4 b = *(const i32x4*)(wp0f + (((kt * 8 + nt) * 64 + lane) << 3));
        #pragma unroll
        for (int rt = 0; rt < 4; ++rt) acc[rt] = MFMA(afr[rt][kt], b, acc[rt]);
      }
      float bias = bp0[nt * 16 + r15];
      #pragma unroll
      for (int rt = 0; rt < 4; ++rt) {
        float mx = fmaxf(fmaxf(acc[rt][0], acc[rt][1]), fmaxf(acc[rt][2], acc[rt][3]));
        mx = fmaxf(mx + bias, 0.0f);                 // relu(max+b) == max(relu(v+b))
        mx = fmaxf(mx, __shfl_xor(mx, 16));          // combine 4+4 edge rows
        if ((g & 1) == 0) {
          u32 row = (u32)(w * 8 + rt * 2 + (g >> 1));
          u32 byte = (row * 512 + 256 + (u32)(nt * 16 + r15) * 2) ^ ((row & 7) << 4);
          *(u16*)(lds + byte) = f2bf(mx);
        }
      }
    }
  }

  // ---- phase B build: u[0:128] = x_dst (bf16, swizzled)
  {
    int i = tid >> 3, part = tid & 7;
    const float* xr = x + (size_t)(d0 + i) * 128 + part * 16;
    f32x4 t0 = *(const f32x4*)(xr + 0);
    f32x4 t1 = *(const f32x4*)(xr + 4);
    f32x4 t2 = *(const f32x4*)(xr + 8);
    f32x4 t3 = *(const f32x4*)(xr + 12);
    u32 sw = (u32)((i & 7) << 4);
    *(i32x4*)(lds + (((u32)i * 512 + (u32)part * 32) ^ sw)) = cvt8(t0, t1);
    *(i32x4*)(lds + (((u32)i * 512 + (u32)part * 32 + 16) ^ sw)) = cvt8(t2, t3);
  }
  __syncthreads();

  // ---- phase B GEMM: h0row = u @ Wcat0 + b0 (K=256)
  f32x4 acc2[4][2] = {};
  for (int kt = 0; kt < 8; ++kt) {
    u32 r0 = (u32)r15, r1 = (u32)(16 + r15);
    i32x4 a0 = *(const i32x4*)(lds + ((r0 * 512 + (u32)kt * 64 + (u32)g * 16) ^ ((r0 & 7) << 4)));
    i32x4 a1 = *(const i32x4*)(lds + ((r1 * 512 + (u32)kt * 64 + (u32)g * 16) ^ ((r1 & 7) << 4)));
    #pragma unroll
    for (int n4 = 0; n4 < 4; ++n4) {
      int nt = w * 4 + n4;
      i32x4 b = *(const i32x4*)(wc0f + (((size_t)(kt * 16 + nt) * 64 + lane) << 3));
      acc2[n4][0] = MFMA(a0, b, acc2[n4][0]);
      acc2[n4][1] = MFMA(a1, b, acc2[n4][1]);
    }
  }

  // ---- epilogue: bias, l2norm (register), bn0 stats, bf16 store
  float vn[4][2][4];
  #pragma unroll
  for (int n4 = 0; n4 < 4; ++n4) {
    float bv = b0v[(w * 4 + n4) * 16 + r15];
    #pragma unroll
    for (int rt = 0; rt < 2; ++rt)
      #pragma unroll
      for (int j = 0; j < 4; ++j) vn[n4][rt][j] = acc2[n4][rt][j] + bv;
  }
  float ssq[2][4];
  #pragma unroll
  for (int rt = 0; rt < 2; ++rt)
    #pragma unroll
    for (int j = 0; j < 4; ++j) {
      float s = 0.0f;
      #pragma unroll
      for (int n4 = 0; n4 < 4; ++n4) s += vn[n4][rt][j] * vn[n4][rt][j];
      s += __shfl_xor(s, 1); s += __shfl_xor(s, 2);
      s += __shfl_xor(s, 4); s += __shfl_xor(s, 8);
      ssq[rt][j] = s;
      if (r15 == 0) rsb[(rt * 16 + g * 4 + j) * 4 + w] = s;
    }
  __syncthreads();   // rowsums ready; u-LDS now dead (all waves past GEMM)

  #pragma unroll
  for (int rt = 0; rt < 2; ++rt)
    #pragma unroll
    for (int j = 0; j < 4; ++j) {
      int r = rt * 16 + g * 4 + j;
      f32x4 q = *(const f32x4*)&rsb[r * 4];
      float rn = 1.0f / fmaxf(sqrtf(q[0] + q[1] + q[2] + q[3]), 1e-12f);
      #pragma unroll
      for (int n4 = 0; n4 < 4; ++n4) vn[n4][rt][j] *= rn;
    }
  // bn0 stats (per-col partial over this block's 32 rows)
  #pragma unroll
  for (int n4 = 0; n4 < 4; ++n4) {
    int col = (w * 4 + n4) * 16 + r15;
    float s1 = 0.0f, s2 = 0.0f;
    #pragma unroll
    for (int rt = 0; rt < 2; ++rt)
      #pragma unroll
      for (int j = 0; j < 4; ++j) { float v = vn[n4][rt][j]; s1 += v; s2 += v * v; }
    s1 += __shfl_xor(s1, 16); s1 += __shfl_xor(s1, 32);
    s2 += __shfl_xor(s2, 16); s2 += __shfl_xor(s2, 32);
    if (g == 0) { atomicAdd(&stat0[col], s1); atomicAdd(&stat0[256 + col], s2); }
  }
  // stage bf16 rows in u-region (plain layout) for coalesced store
  #pragma unroll
  for (int n4 = 0; n4 < 4; ++n4)
    #pragma unroll
    for (int rt = 0; rt < 2; ++rt)
      #pragma unroll
      for (int j = 0; j < 4; ++j)
        *(u16*)(lds + (u32)(rt * 16 + g * 4 + j) * 512 + (u32)((w * 4 + n4) * 16 + r15) * 2)
            = f2bf(vn[n4][rt][j]);
  __syncthreads();
  {
    int i = tid >> 3, c8 = tid & 7;
    const char* srcp = lds + i * 512 + c8 * 64;
    u16* dst = h0 + (size_t)(d0 + i) * 256 + c8 * 32;
    #pragma unroll
    for (int c = 0; c < 4; ++c)
      *(i32x4*)(dst + c * 8) = *(const i32x4*)(srcp + c * 16);
  }
}

// ---------------- gemm64: Out = [relu(affine(Ain))] @ Bf + bias ----------------
template <bool RELU_OUT, bool STATS, bool H2OUT>
__global__ __launch_bounds__(256, 4)
void gemm64(const u16* __restrict__ Ain, const float* __restrict__ ss,
            const u16* __restrict__ Bf, const float* __restrict__ bias,
            u16* __restrict__ Out, float* __restrict__ stat,
            u16* __restrict__ H2out) {
  __shared__ __align__(16) char lds[34816];  // A-stage/tb share [0,32768); scs @32768
  u16* tb = (u16*)lds;                       // reused after MFMA barrier
  float* scs = (float*)(lds + 32768);
  int tid = threadIdx.x, lane = tid & 63, w = tid >> 6;
  int r15 = lane & 15, g = lane >> 4;
  int d0 = blockIdx.x * 64;
  scs[tid] = ss[tid];
  scs[256 + tid] = ss[256 + tid];
  __syncthreads();

  // A-build: relu(scale*a + shift) -> swizzled bf16 [64][256]
  {
    int i = tid >> 2, part = tid & 3;
    const u16* ar = Ain + (size_t)(d0 + i) * 256 + part * 64;
    u32 sw = (u32)((i & 7) << 4), rowb = (u32)i * 512;
    for (int cc = 0; cc < 8; ++cc) {
      union { i32x4 q; u16 h[8]; } in, out;
      in.q = *(const i32x4*)(ar + cc * 8);
      #pragma unroll
      for (int j = 0; j < 8; ++j) {
        int k = part * 64 + cc * 8 + j;
        float v = fmaxf(bf2f(in.h[j]) * scs[k] + scs[256 + k], 0.0f);
        out.h[j] = f2bf(v);
      }
      *(i32x4*)(lds + ((rowb + (u32)(part * 64 + cc * 8) * 2) ^ sw)) = out.q;
    }
  }
  __syncthreads();

  f32x4 acc[4][4] = {};   // [n4][rt]
  for (int kt = 0; kt < 8; ++kt) {
    i32x4 a[4];
    #pragma unroll
    for (int rt = 0; rt < 4; ++rt) {
      u32 r = (u32)(rt * 16 + r15);
      a[rt] = *(const i32x4*)(lds + ((r * 512 + (u32)kt * 64 + (u32)g * 16) ^ ((r & 7) << 4)));
    }
    #pragma unroll
    for (int n4 = 0; n4 < 4; ++n4) {
      int nt = w * 4 + n4;
      i32x4 b = *(const i32x4*)(Bf + (((size_t)(kt * 16 + nt) * 64 + lane) << 3));
      #pragma unroll
      for (int rt = 0; rt < 4; ++rt) acc[n4][rt] = MFMA(a[rt], b, acc[n4][rt]);
    }
  }
  __syncthreads();   // all waves done reading A-stage

  if constexpr (H2OUT) {
    if (d0 < CN2) {
      int i = tid >> 2, part = tid & 3;
      u16* orow = H2out + (size_t)(d0 + i) * 256 + part * 64;
      u32 sw = (u32)((i & 7) << 4);
      #pragma unroll
      for (int cc = 0; cc < 8; ++cc)
        *(i32x4*)(orow + cc * 8) =
            *(const i32x4*)(lds + (((u32)i * 512 + (u32)(part * 64 + cc * 8) * 2) ^ sw));
    }
    __syncthreads();
  }

  #pragma unroll
  for (int n4 = 0; n4 < 4; ++n4) {
    int col = (w * 4 + n4) * 16 + r15;
    float bv = bias[col];
    #pragma unroll
    for (int rt = 0; rt < 4; ++rt)
      #pragma unroll
      for (int j = 0; j < 4; ++j) {
        float v = acc[n4][rt][j] + bv;
        if (RELU_OUT) v = fmaxf(v, 0.0f);
        tb[(rt * 16 + g * 4 + j) * 256 + col] = f2bf(v);
      }
  }
  __syncthreads();

  {
    int i = tid >> 2, part = tid & 3;
    u16* orow = Out + (size_t)(d0 + i) * 256 + part * 64;
    const u16* trow = tb + i * 256 + part * 64;
    #pragma unroll
    for (int cc = 0; cc < 8; ++cc)
      *(i32x4*)(orow + cc * 8) = *(const i32x4*)(trow + cc * 8);
  }
  if (STATS) {
    int c = tid; float s1 = 0.0f, s2 = 0.0f;
    for (int r = 0; r < 64; ++r) { float v = bf2f(tb[r * 256 + c]); s1 += v; s2 += v * v; }
    atomicAdd(&stat[c], s1); atomicAdd(&stat[256 + c], s2);
  }
}

// ---------------- K6: fused layer-1 (32 dst / block) ----------------
__global__ __launch_bounds__(256, 2)
void k6_layer1(const int* __restrict__ esrc1, const u16* __restrict__ m1,
               const u16* __restrict__ h2, const u16* __restrict__ wc1f,
               const u16* __restrict__ wlatf, const float* __restrict__ b1v,
               const float* __restrict__ blat, float* __restrict__ zz,
               float* __restrict__ statl) {
  __shared__ __align__(16) char lds[81920];
  // u1 swizzled bf16 [32][512] @0; zbuf f32 [32][256] @32768; u2 swizzled bf16 [32][256] @65536
  float* zbuf = (float*)(lds + 32768);
  int tid = threadIdx.x, lane = tid & 63, w = tid >> 6;
  int r15 = lane & 15, g = lane >> 4;
  int d0 = blockIdx.x * 32;

  // ---- build u1 = [h2_dst | max-pool(m1 rows)]
  {
    int i = tid >> 3, part = tid & 7;
    u32 sw = (u32)((i & 7) << 4);
    const u16* hrow = h2 + (size_t)(d0 + i) * 256 + part * 32;
    #pragma unroll
    for (int cc = 0; cc < 4; ++cc) {
      i32x4 q = *(const i32x4*)(hrow + cc * 8);
      *(i32x4*)(lds + (((u32)i * 1024 + (u32)(part * 32 + cc * 8) * 2) ^ sw)) = q;
    }
    float mx[32];
    #pragma unroll
    for (int c = 0; c < 32; ++c) mx[c] = -1e30f;
    for (int e = 0; e < 10; ++e) {
      int src = esrc1[(d0 + i) * 10 + e];
      const u16* mrow = m1 + (size_t)src * 256 + part * 32;
      #pragma unroll
      for (int cc = 0; cc < 4; ++cc) {
        union { i32x4 q; u16 h[8]; } pk;
        pk.q = *(const i32x4*)(mrow + cc * 8);
        #pragma unroll
        for (int j = 0; j < 8; ++j) mx[cc * 8 + j] = fmaxf(mx[cc * 8 + j], bf2f(pk.h[j]));
      }
    }
    #pragma unroll
    for (int cc = 0; cc < 4; ++cc) {
      union { i32x4 q; u16 h[8]; } pk;
      #pragma unroll
      for (int j = 0; j < 8; ++j) pk.h[j] = f2bf(mx[cc * 8 + j]);
      *(i32x4*)(lds + (((u32)i * 1024 + (u32)(256 + part * 32 + cc * 8) * 2) ^ sw)) = pk.q;
    }
  }
  __syncthreads();

  // ---- GEMM1: z = u1 @ Wcat1 + b1 -> zbuf
  {
    f32x4 acc[4][2] = {};
    for (int kt = 0; kt < 16; ++kt) {
      u32 r0 = (u32)r15, r1 = (u32)(16 + r15);
      i32x4 a0 = *(const i32x4*)(lds + ((r0 * 1024 + (u32)kt * 64 + (u32)g * 16) ^ ((r0 & 7) << 4)));
      i32x4 a1 = *(const i32x4*)(lds + ((r1 * 1024 + (u32)kt * 64 + (u32)g * 16) ^ ((r1 & 7) << 4)));
      #pragma unroll
      for (int n4 = 0; n4 < 4; ++n4) {
        int nt = w * 4 + n4;
        i32x4 b = *(const i32x4*)(wc1f + (((size_t)(kt * 16 + nt) * 64 + lane) << 3));
        acc[n4][0] = MFMA(a0, b, acc[n4][0]);
        acc[n4][1] = MFMA(a1, b, acc[n4][1]);
      }
    }
    #pragma unroll
    for (int n4 = 0; n4 < 4; ++n4) {
      int col = (w * 4 + n4) * 16 + r15;
      float bv = b1v[col];
      #pragma unroll
      for (int rt = 0; rt < 2; ++rt)
        #pragma unroll
        for (int j = 0; j < 4; ++j)
          zbuf[(rt * 16 + g * 4 + j) * 256 + col] = acc[n4][rt][j] + bv;
    }
  }
  __syncthreads();

  // ---- l2norm -> u2 (swizzled bf16 @65536)
  {
    int i = tid >> 3, part = tid & 7;
    float* zr = zbuf + i * 256 + part * 32;
    float v[32]; float ss = 0.0f;
    #pragma unroll
    for (int c = 0; c < 32; ++c) { v[c] = zr[c]; ss += v[c] * v[c]; }
    ss += __shfl_xor(ss, 1); ss += __shfl_xor(ss, 2); ss += __shfl_xor(ss, 4);
    float rn = 1.0f / fmaxf(sqrtf(ss), 1e-12f);
    u32 sw = (u32)((i & 7) << 4);
    #pragma unroll
    for (int cc = 0; cc < 4; ++cc) {
      union { i32x4 q; u16 h[8]; } pk;
      #pragma unroll
      for (int j = 0; j < 8; ++j) pk.h[j] = f2bf(v[cc * 8 + j] * rn);
      *(i32x4*)(lds + 65536 + (((u32)i * 512 + (u32)(part * 32 + cc * 8) * 2) ^ sw)) = pk.q;
    }
  }
  __syncthreads();

  // ---- GEMM2: zz_blk = u2 @ Wlat + blat -> zbuf (overwrite)
  {
    f32x4 acc[4][2] = {};
    for (int kt = 0; kt < 8; ++kt) {
      u32 r0 = (u32)r15, r1 = (u32)(16 + r15);
      i32x4 a0 = *(const i32x4*)(lds + 65536 + ((r0 * 512 + (u32)kt * 64 + (u32)g * 16) ^ ((r0 & 7) << 4)));
      i32x4 a1 = *(const i32x4*)(lds + 65536 + ((r1 * 512 + (u32)kt * 64 + (u32)g * 16) ^ ((r1 & 7) << 4)));
      #pragma unroll
      for (int n4 = 0; n4 < 4; ++n4) {
        int nt = w * 4 + n4;
        i32x4 b = *(const i32x4*)(wlatf + (((size_t)(kt * 16 + nt) * 64 + lane) << 3));
        acc[n4][0] = MFMA(a0, b, acc[n4][0]);
        acc[n4][1] = MFMA(a1, b, acc[n4][1]);
      }
    }
    #pragma unroll
    for (int n4 = 0; n4 < 4; ++n4) {
      int col = (w * 4 + n4) * 16 + r15;
      float bv = blat[col];
      #pragma unroll
      for (int rt = 0; rt < 2; ++rt)
        #pragma unroll
        for (int j = 0; j < 4; ++j)
          zbuf[(rt * 16 + g * 4 + j) * 256 + col] = acc[n4][rt][j] + bv;
    }
  }
  __syncthreads();

  // ---- write zz + bnl stats
  {
    int i = tid >> 3, part = tid & 7;
    float* zr = zbuf + i * 256 + part * 32;
    float* orow = zz + (size_t)(d0 + i) * 256 + part * 32;
    #pragma unroll
    for (int c = 0; c < 32; c += 4) *(f32x4*)(orow + c) = *(const f32x4*)(zr + c);
  }
  {
    int c = tid; float s1 = 0.0f, s2 = 0.0f;
    for (int r = 0; r < 32; ++r) { float v = zbuf[r * 256 + c]; s1 += v; s2 += v * v; }
    atomicAdd(&statl[c], s1); atomicAdd(&statl[256 + c], s2);
  }
}

// ---------------- K7: out = bnl(zz) ----------------
__global__ void k7_out(const float* __restrict__ zz, const float* __restrict__ ssl,
                       float* __restrict__ out) {
  int idx = blockIdx.x * 256 + threadIdx.x;
  int e0 = idx * 4;
  int c = e0 & 255;
  f32x4 v = *(const f32x4*)(zz + e0);
  f32x4 sc = *(const f32x4*)(ssl + c);
  f32x4 sh = *(const f32x4*)(ssl + 256 + c);
  *(f32x4*)(out + e0) = v * sc + sh;
}

extern "C" void kernel_launch(void* const* d_in, const int* in_sizes, int n_in,
                              void* d_out, int out_size, void* d_ws, size_t ws_size,
                              hipStream_t stream) {
  const float* x     = (const float*)d_in[0];
  const int*   es0   = (const int*)d_in[1];
  const int*   es1   = (const int*)d_in[3];
  const float* Wp0   = (const float*)d_in[5];
  const float* bp0   = (const float*)d_in[6];
  const float* Ws0   = (const float*)d_in[7];
  const float* Wn0   = (const float*)d_in[8];
  const float* b0v   = (const float*)d_in[9];
  const float* Wp1   = (const float*)d_in[10];
  const float* bp1   = (const float*)d_in[11];
  const float* Ws1   = (const float*)d_in[12];
  const float* Wn1   = (const float*)d_in[13];
  const float* b1v   = (const float*)d_in[14];
  const float* gbn0  = (const float*)d_in[15];
  const float* bebn0 = (const float*)d_in[16];
  const float* Wh    = (const float*)d_in[17];
  const float* bh    = (const float*)d_in[18];
  const float* gbnh  = (const float*)d_in[19];
  const float* bebnh = (const float*)d_in[20];
  const float* Wlat  = (const float*)d_in[21];
  const float* blat  = (const float*)d_in[22];
  const float* gbnl  = (const float*)d_in[23];
  const float* bebnl = (const float*)d_in[24];

  char* ws = (char*)d_ws;
  u16* h0    = (u16*)(ws + H0_OFF);
  u16* tban  = (u16*)(ws + T_OFF);
  u16* m1    = (u16*)(ws + H0_OFF);   // reuse: h0 dead after hidden GEMM
  u16* h2    = (u16*)(ws + H2_OFF);
  float* zz  = (float*)(ws + ZZ_OFF);
  u16* wp0f  = (u16*)(ws + WP0F_OFF);
  u16* wc0f  = (u16*)(ws + WC0F_OFF);
  u16* whf   = (u16*)(ws + WHF_OFF);
  u16* wp1f  = (u16*)(ws + WP1F_OFF);
  u16* wc1f  = (u16*)(ws + WC1F_OFF);
  u16* wlatf = (u16*)(ws + WLATF_OFF);
  float* stat = (float*)(ws + STAT_OFF);
  float* ssv  = (float*)(ws + SS_OFF);

  hipMemsetAsync(stat, 0, 6 * 256 * sizeof(float), stream);
  kprep<<<64, 256, 0, stream>>>(Wp0, Ws0, Wn0, Wh, Wp1, Ws1, Wn1, Wlat,
                                wp0f, wc0f, whf, wp1f, wc1f, wlatf);
  k1_layer0<<<CN1 / 32, 256, 0, stream>>>(x, es0, wp0f, wc0f, bp0, b0v, h0, stat);
  kfin<<<1, 256, 0, stream>>>(stat, 1.0f / CN1, gbn0, bebn0, ssv);
  gemm64<false, true, false><<<CN1 / 64, 256, 0, stream>>>(h0, ssv, whf, bh, tban,
                                                           stat + 512, nullptr);
  kfin<<<1, 256, 0, stream>>>(stat + 512, 1.0f / CN1, gbnh, bebnh, ssv + 512);
  gemm64<true, false, true><<<CN1 / 64, 256, 0, stream>>>(tban, ssv + 512, wp1f, bp1,
                                                          m1, nullptr, h2);
  k6_layer1<<<CN2 / 32, 256, 0, stream>>>(es1, m1, h2, wc1f, wlatf, b1v, blat, zz,
                                          stat + 1024);
  kfin<<<1, 256, 0, stream>>>(stat + 1024, 1.0f / CN2, gbnl, bebnl, ssv + 1024);
  k7_out<<<out_size / 1024, 256, 0, stream>>>(zz, ssv + 1024, (float*)d_out);
  (void)in_sizes; (void)n_in; (void)ws_size;
}